// Round 1
// baseline (1510.264 us; speedup 1.0000x reference)
//
#include <hip/hip_runtime.h>
#include <hip/hip_bf16.h>

// HMS2 fused: full-image 2-layer strided conv (tiling proven equivalent).
// Image [2304,2304,3] int32 -> /255 -> conv1 3x3 s2 pad(0,1) -> relu ->
// conv2 3x3 s2 pad(0,1) -> relu -> out NCHW [128,576,576] fp32.

#define IMG 2304
#define H1  1152          // conv1 output side
#define H2  576           // conv2 output side
#define C1  64
#define C2  128
#define TS  8             // conv2 outputs per block side (8x8 tile)
#define NTB (H2/TS)       // 72 tiles per axis
#define C1T 17            // conv1 tile side  (2*TS+1)
#define C1S (C1T*C1T)     // 289 conv1 spatial positions
#define C1P 292           // padded spatial stride for conv1 LDS
#define IT  35            // image tile side  (4*TS+3)

__global__ __launch_bounds__(256) void hms2_fused(
    const int*   __restrict__ img,
    const float* __restrict__ W1,
    const float* __restrict__ b1,
    const float* __restrict__ W2,
    const float* __restrict__ b2,
    float*       __restrict__ out)
{
    __shared__ float          s_img[IT*IT*3];   // 14700 B
    __shared__ float          s_w1[27*C1];      //  6912 B
    __shared__ __hip_bfloat16 s_c1[C1*C1P];     // 37376 B  -> total ~59 KB

    const int tid   = threadIdx.x;
    const int tileY = blockIdx.x / NTB;
    const int tileX = blockIdx.x % NTB;
    const int e0y = tileY * TS, e0x = tileX * TS;   // conv2 tile origin
    const int r0  = 2*e0y,      q0  = 2*e0x;        // conv1 tile origin
    const int iy0 = 4*e0y,      ix0 = 4*e0x;        // image tile origin

    // ---- stage W1 (3*3*3*64 = 1728 floats) ----
    for (int i = tid; i < 27*C1; i += 256) s_w1[i] = W1[i];

    // ---- stage image tile, normalized, zero-padded past image edge ----
    for (int i = tid; i < IT*IT*3; i += 256) {
        int ch = i % 3;
        int p  = i / 3;
        int r  = p / IT, c = p % IT;
        int gy = iy0 + r, gx = ix0 + c;
        float v = 0.0f;
        if (gy < IMG && gx < IMG)
            v = (float)img[((size_t)gy*IMG + gx)*3 + ch] * (1.0f/255.0f);
        s_img[i] = v;
    }
    __syncthreads();

    // ---- conv1: 17x17x64 tile -> LDS (bf16), ReLU(b1 + conv) ----
    // lanes: c = idx&63 (consecutive -> W1 reads conflict-free, img reads
    // wave-uniform broadcast)
    for (int idx = tid; idx < C1S*C1; idx += 256) {
        int s = idx >> 6;         // 0..288 spatial
        int c = idx & 63;         // channel
        int r = s / C1T, q = s % C1T;
        float v = 0.0f;
        if (r0 + r < H1 && q0 + q < H1) {       // conv1 pad rows/cols are true zeros
            float sum = b1[c];
            #pragma unroll
            for (int ky = 0; ky < 3; ++ky) {
                #pragma unroll
                for (int kx = 0; kx < 3; ++kx) {
                    const float* ip = &s_img[((2*r+ky)*IT + (2*q+kx))*3];
                    const float* wp = &s_w1[(ky*3+kx)*3*C1 + c];
                    sum = fmaf(ip[0], wp[0],     sum);
                    sum = fmaf(ip[1], wp[C1],    sum);
                    sum = fmaf(ip[2], wp[2*C1],  sum);
                }
            }
            v = fmaxf(sum, 0.0f);
        }
        s_c1[c*C1P + s] = __float2bfloat16(v);
    }
    __syncthreads();

    // ---- conv2: lanes = 64 spatial (8x8), wave w -> channels [32w, 32w+32) ----
    const int s  = tid & 63;
    const int h  = s >> 3, w = s & 7;
    const int cg = __builtin_amdgcn_readfirstlane(tid >> 6);  // uniform wave id
    const float* w2base = W2 + cg * 32;

    float acc[32];
    #pragma unroll
    for (int j = 0; j < 32; ++j) acc[j] = 0.0f;

    #pragma unroll
    for (int ky = 0; ky < 3; ++ky) {
        #pragma unroll
        for (int kx = 0; kx < 3; ++kx) {
            const __hip_bfloat16* ap = &s_c1[(2*h+ky)*C1T + (2*w+kx)];
            const float* wp = w2base + (size_t)((ky*3+kx)*C1) * C2;
            #pragma unroll 4
            for (int ci = 0; ci < C1; ++ci) {
                float a = __bfloat162float(ap[(size_t)ci*C1P]);
                const float* wq = wp + ci*C2;   // wave-uniform address
                #pragma unroll
                for (int j = 0; j < 32; ++j)
                    acc[j] = fmaf(a, wq[j], acc[j]);
            }
        }
    }

    // ---- epilogue: bias + ReLU, NCHW store ----
    const int gy = e0y + h, gx = e0x + w;
    #pragma unroll
    for (int j = 0; j < 32; ++j) {
        int c = cg*32 + j;
        float v = fmaxf(acc[j] + b2[c], 0.0f);
        out[(size_t)c*(H2*H2) + (size_t)gy*H2 + gx] = v;
    }
}

extern "C" void kernel_launch(void* const* d_in, const int* in_sizes, int n_in,
                              void* d_out, int out_size, void* d_ws, size_t ws_size,
                              hipStream_t stream) {
    const int*   img = (const int*)  d_in[0];
    const float* W1  = (const float*)d_in[1];
    const float* b1  = (const float*)d_in[2];
    const float* W2  = (const float*)d_in[3];
    const float* b2  = (const float*)d_in[4];
    float*       out = (float*)d_out;

    hms2_fused<<<dim3(NTB*NTB), dim3(256), 0, stream>>>(img, W1, b1, W2, b2, out);
}